// Round 18
// baseline (68.696 us; speedup 1.0000x reference)
//
#include <hip/hip_runtime.h>
#include <hip/hip_bf16.h>

#define BATCH    32768
#define HD       256
#define G        1600          // z-grid points per te slice
#define NTE      9             // distinct te values: 0, 0.125, ..., 1.0
#define NBLK     (NTE * (G / 32))   // 450 blocks
#define ZMIN     -20.0f
#define HSTEP    0.025f        // 40/G
#define INVH     40.0f         // G/40

#define SCL    2.8853900817779268f   // 2*log2(e): tanh(x) = 1 - 2/(exp2(SCL*x)+1)
#define SCLINV 0.3465735902799726f   // 1/SCL

typedef short  short8 __attribute__((ext_vector_type(8)));
typedef float  f32x16 __attribute__((ext_vector_type(16)));
typedef float  f32x2  __attribute__((ext_vector_type(2)));

// scalar f32 -> bf16 RNE
__device__ __forceinline__ unsigned short f2bf(float f) {
    unsigned u = __float_as_uint(f);
    return (unsigned short)((u + 0x7FFFu + ((u >> 16) & 1u)) >> 16);
}

// packed f32 pair -> bf16x2 (v_cvt_pk_bf16_f32)
__device__ __forceinline__ unsigned pk2(float a, float b) {
    __hip_bfloat162 h = __float22bfloat162_rn(make_float2(a, b));
    return *reinterpret_cast<unsigned*>(&h);
}

// fused persistent kernel: prepack -> spin-barrier -> tabulate -> spin-barrier -> integrate
// Co-residency guarantee (deadlock-free spin): LDS 40,960 B -> 4 blocks/CU and
// __launch_bounds__(512,4) caps VGPR<=128 -> >=2 blocks/CU => capacity >=512 > 450.
__global__ __launch_bounds__(512, 4)
void cnf1d_fused(const float* __restrict__ z0,
                 const float* __restrict__ W1,
                 const float* __restrict__ b1,
                 const float* __restrict__ W2,
                 const float* __restrict__ b2,
                 const float* __restrict__ W3,
                 const float* __restrict__ b3,
                 unsigned short* __restrict__ wsA,
                 float2* __restrict__ tbl,
                 unsigned* __restrict__ ctr,     // [2], zeroed by memsetAsync per call
                 float* __restrict__ out)
{
    __shared__ __align__(16) short Abuf[64 * 256];            // 32 KB
    __shared__ float w1zS[HD], w1tS[HD], b1S[HD], w0S[HD];    // 4 KB
    __shared__ float b2sc[HD], w3t[HD];                       // 2 KB
    __shared__ float2 kz[8][32];                              // 2 KB -> 40,960 B

    const int tid = threadIdx.x;
    const int bid = blockIdx.x;

    // ===== phase 0: prepack SCL*W2^T into bf16 A-frag order (blocks 0..127) =====
    if (bid < 128) {
        const int gt = bid * 512 + tid;
        const int k = gt >> 8, j = gt & 255;
        const unsigned short b = f2bf(SCL * W2[k * HD + j]);
        const int kstep = k >> 4, kl = k & 15, hi2 = kl >> 3, i = kl & 7;
        const int mt = j >> 5, jl = j & 31;
        wsA[(((mt * 16) + kstep) * 64 + (hi2 * 32 + jl)) * 8 + i] = b;
        __syncthreads();
        if (tid == 0) {
            __threadfence();                                   // agent-scope release
            __hip_atomic_fetch_add(&ctr[0], 1u, __ATOMIC_RELEASE, __HIP_MEMORY_SCOPE_AGENT);
        }
    }
    // barrier 0: wait for all 128 prepack blocks
    if (tid == 0) {
        while (__hip_atomic_load(&ctr[0], __ATOMIC_ACQUIRE, __HIP_MEMORY_SCOPE_AGENT) < 128u)
            __builtin_amdgcn_s_sleep(2);
    }
    __syncthreads();

    // ===== phase 1: tabulate f / df/dz on the (te, z) grid (all 450 blocks) =====
    {
        const int lane = tid & 63;
        const int c    = lane & 31;
        const int hi   = lane >> 5;
        const int wid  = tid >> 6;        // wave: j in [wid*32, wid*32+32)
        const int s    = tid & 31;        // grid point within chunk
        const int fb   = tid >> 5;        // staging feature block 0..15
        const int teI  = bid / (G / 32);
        const int zblk = bid % (G / 32);

        const float te = teI * 0.125f;
        const float zv = ZMIN + (float)(zblk * 32 + s) * HSTEP;

        if (tid < HD) {
            const float w0 = W1[tid];
            w1zS[tid] = SCL * w0;
            w1tS[tid] = SCL * W1[HD + tid];
            b1S[tid]  = SCL * b1[tid];
            w0S[tid]  = w0;
            b2sc[tid] = SCL * b2[tid];
            w3t[tid]  = W3[tid];
        }
        const float b3v = b3[0];

        // coalesced fragment load: 16 x dwordx4 per lane
        const short8* __restrict__ wsA8 = (const short8*)wsA;
        short8 w2f[16];
        #pragma unroll
        for (int kk = 0; kk < 16; ++kk)
            w2f[kk] = wsA8[(wid * 16 + kk) * 64 + lane];
        __syncthreads();

        const f32x2 one2 = {1.f, 1.f};
        const f32x2 m2   = {-2.f, -2.f};
        uint4* __restrict__ Ab4 = (uint4*)Abuf;
        const short8* __restrict__ Ab8 = (const short8*)Abuf;
        const int jb = wid * 32 + hi * 4;

        // phase 1a: h1/th1 for the 32 grid points
        {
            const f32x2 zc2 = {zv, zv};
            const f32x2 te2 = {te, te};
            #pragma unroll
            for (int g2 = 0; g2 < 2; ++g2) {
                const int j0 = fb * 16 + g2 * 8;
                const float4 wzA = *(const float4*)&w1zS[j0];
                const float4 wzB = *(const float4*)&w1zS[j0 + 4];
                const float4 wtA = *(const float4*)&w1tS[j0];
                const float4 wtB = *(const float4*)&w1tS[j0 + 4];
                const float4 bbA = *(const float4*)&b1S[j0];
                const float4 bbB = *(const float4*)&b1S[j0 + 4];
                const float4 w0A = *(const float4*)&w0S[j0];
                const float4 w0B = *(const float4*)&w0S[j0 + 4];
                const f32x2 wz[4]  = {{wzA.x, wzA.y}, {wzA.z, wzA.w}, {wzB.x, wzB.y}, {wzB.z, wzB.w}};
                const f32x2 wt[4]  = {{wtA.x, wtA.y}, {wtA.z, wtA.w}, {wtB.x, wtB.y}, {wtB.z, wtB.w}};
                const f32x2 bb[4]  = {{bbA.x, bbA.y}, {bbA.z, bbA.w}, {bbB.x, bbB.y}, {bbB.z, bbB.w}};
                const f32x2 w0p[4] = {{w0A.x, w0A.y}, {w0A.z, w0A.w}, {w0B.x, w0B.y}, {w0B.z, w0B.w}};
                f32x2 hh[4], th[4];
                #pragma unroll
                for (int pp = 0; pp < 4; ++pp) {
                    const f32x2 a = __builtin_elementwise_fma(zc2, wz[pp],
                                      __builtin_elementwise_fma(te2, wt[pp], bb[pp]));
                    f32x2 ev; ev.x = __builtin_amdgcn_exp2f(a.x);
                              ev.y = __builtin_amdgcn_exp2f(a.y);
                    const f32x2 e1 = ev + one2;
                    f32x2 rv; rv.x = __builtin_amdgcn_rcpf(e1.x);
                              rv.y = __builtin_amdgcn_rcpf(e1.y);
                    const f32x2 h  = __builtin_elementwise_fma(m2, rv, one2);   // tanh
                    const f32x2 t1 = __builtin_elementwise_fma(-h, h, one2);    // 1 - h^2
                    hh[pp] = h;
                    th[pp] = t1 * w0p[pp];
                }
                uint4 vU, vT;
                vU.x = pk2(hh[0].x, hh[0].y);  vU.y = pk2(hh[1].x, hh[1].y);
                vU.z = pk2(hh[2].x, hh[2].y);  vU.w = pk2(hh[3].x, hh[3].y);
                vT.x = pk2(th[0].x, th[0].y);  vT.y = pk2(th[1].x, th[1].y);
                vT.z = pk2(th[2].x, th[2].y);  vT.w = pk2(th[3].x, th[3].y);
                const int gr = j0 >> 3;
                Ab4[gr * 64 + s]      = vU;
                Ab4[gr * 64 + 32 + s] = vT;
            }
        }
        __syncthreads();

        // phase 1b: MFMA
        f32x16 accU, accT;
        #pragma unroll
        for (int rq = 0; rq < 4; ++rq) {
            const float4 bq = *(const float4*)&b2sc[jb + rq * 8];
            accU[rq * 4 + 0] = bq.x;  accU[rq * 4 + 1] = bq.y;
            accU[rq * 4 + 2] = bq.z;  accU[rq * 4 + 3] = bq.w;
            accT[rq * 4 + 0] = 0.f;   accT[rq * 4 + 1] = 0.f;
            accT[rq * 4 + 2] = 0.f;   accT[rq * 4 + 3] = 0.f;
        }
        #pragma unroll
        for (int kk = 0; kk < 16; ++kk) {
            const short8 hU = Ab8[(kk * 2 + hi) * 64 + c];
            const short8 hT = Ab8[(kk * 2 + hi) * 64 + 32 + c];
            accU = __builtin_amdgcn_mfma_f32_32x32x16_bf16(w2f[kk], hU, accU, 0, 0, 0);
            accT = __builtin_amdgcn_mfma_f32_32x32x16_bf16(w2f[kk], hT, accT, 0, 0, 0);
        }

        // phase 1c: epilogue
        f32x2 pz2 = {0.f, 0.f}, pd2 = {0.f, 0.f};
        #pragma unroll
        for (int rq = 0; rq < 4; ++rq) {
            const float4 w3q = *(const float4*)&w3t[jb + rq * 8];
            const f32x2 w3p[2] = {{w3q.x, w3q.y}, {w3q.z, w3q.w}};
            #pragma unroll
            for (int pr = 0; pr < 2; ++pr) {
                const int r = rq * 4 + pr * 2;
                const f32x2 u2 = {accU[r], accU[r + 1]};
                const f32x2 t2 = {accT[r], accT[r + 1]};
                f32x2 ev; ev.x = __builtin_amdgcn_exp2f(u2.x);
                          ev.y = __builtin_amdgcn_exp2f(u2.y);
                const f32x2 e1 = ev + one2;
                f32x2 rv; rv.x = __builtin_amdgcn_rcpf(e1.x);
                          rv.y = __builtin_amdgcn_rcpf(e1.y);
                const f32x2 h2 = __builtin_elementwise_fma(m2, rv, one2);
                const f32x2 hq = h2 * h2;
                const f32x2 th2 = __builtin_elementwise_fma(-hq, t2, t2);
                pz2 = __builtin_elementwise_fma(h2,  w3p[pr], pz2);
                pd2 = __builtin_elementwise_fma(th2, w3p[pr], pd2);
            }
        }
        float pdz = pz2.x + pz2.y;
        float pdd = (pd2.x + pd2.y) * SCLINV;
        pdz += __shfl_xor(pdz, 32);
        pdd += __shfl_xor(pdd, 32);
        if (hi == 0) kz[wid][c] = make_float2(pdz, pdd);
        __syncthreads();

        if (tid < 32) {
            float kzs = b3v, kds = 0.f;
            #pragma unroll
            for (int w = 0; w < 8; ++w) {
                const float2 a = kz[w][tid];
                kzs += a.x; kds += a.y;
            }
            tbl[teI * G + zblk * 32 + tid] = make_float2(kzs, kds);
        }
    }
    __syncthreads();
    if (tid == 0) {
        __threadfence();                                       // agent-scope release
        __hip_atomic_fetch_add(&ctr[1], 1u, __ATOMIC_RELEASE, __HIP_MEMORY_SCOPE_AGENT);
    }

    // ===== phase 2: RK4 integrate (blocks 0..63, 512 samples each) =====
    if (bid >= BATCH / 512) return;            // others exit, freeing CUs

    if (tid == 0) {
        while (__hip_atomic_load(&ctr[1], __ATOMIC_ACQUIRE, __HIP_MEMORY_SCOPE_AGENT) < (unsigned)NBLK)
            __builtin_amdgcn_s_sleep(2);
    }
    __syncthreads();

    {
        float2* sl = (float2*)Abuf;            // alias: 12.8 KB of the 32 KB buffer
        const int sid = bid * 512 + tid;

        float zb = z0[sid];
        float zc = zb, skz = 0.f, skd = 0.f, dacc = 0.f;
        const float dt = 0.25f;
        int prev = -1;

        for (int it = 0; it < 16; ++it) {
            const int st = it >> 2, e = it & 3;
            const int idx = 2 * st + ((e == 0) ? 0 : (e == 3) ? 2 : 1);
            if (idx != prev) {                 // block-uniform condition
                __syncthreads();
                for (int g = tid; g < G; g += 512)
                    sl[g] = tbl[idx * G + g];
                __syncthreads();
                prev = idx;
            }
            float xf = (zc - ZMIN) * INVH;
            xf = fminf(fmaxf(xf, 0.0f), (float)(G - 1));
            int i0 = (int)xf;
            if (i0 > G - 2) i0 = G - 2;
            const float w  = xf - (float)i0;
            const float2 a = sl[i0];
            const float2 b = sl[i0 + 1];
            const float kzv = fmaf(w, b.x - a.x, a.x);
            const float kdv = fmaf(w, b.y - a.y, a.y);

            const float cw = (e == 1 || e == 2) ? 2.f : 1.f;
            skz += cw * kzv;
            skd += cw * kdv;
            if (e < 3) {
                zc = fmaf((e == 2) ? dt : 0.5f * dt, kzv, zb);
            } else {
                zb   = fmaf(dt / 6.f, skz, zb);
                zc   = zb;
                dacc = fmaf(dt / 6.f, skd, dacc);
                skz = 0.f; skd = 0.f;
            }
        }

        out[sid]         = zb;      // zf
        out[BATCH + sid] = dacc;    // div_int
    }
}

extern "C" void kernel_launch(void* const* d_in, const int* in_sizes, int n_in,
                              void* d_out, int out_size, void* d_ws, size_t ws_size,
                              hipStream_t stream) {
    const float* z0 = (const float*)d_in[0];
    const float* W1 = (const float*)d_in[1];
    const float* b1 = (const float*)d_in[2];
    const float* W2 = (const float*)d_in[3];
    const float* b2 = (const float*)d_in[4];
    const float* W3 = (const float*)d_in[5];
    const float* b3 = (const float*)d_in[6];
    float* out = (float*)d_out;

    float2* tbl = (float2*)d_ws;                                    // 115,200 B @ 0
    unsigned* ctr = (unsigned*)((char*)d_ws + 115200);              // 8 B
    unsigned short* wsA = (unsigned short*)((char*)d_ws + 131072);  // 128 KB frag W2^T

    hipMemsetAsync(ctr, 0, 8, stream);    // zero spin-barrier counters each call
    hipLaunchKernelGGL(cnf1d_fused, dim3(NBLK), dim3(512), 0, stream,
                       z0, W1, b1, W2, b2, W3, b3, wsA, tbl, ctr, out);
}

// Round 19
// 19.946 us; speedup vs baseline: 3.4440x; 3.4440x over previous
//
#include <hip/hip_runtime.h>
#include <hip/hip_bf16.h>

#define BATCH    32768
#define HD       256
#define G        1024          // z-grid points per te slice
#define NTE      9             // distinct te values: 0, 0.125, ..., 1.0
#define ZMIN     -16.0f
#define HSTEP    0.03125f      // 32/G
#define INVH     32.0f         // G/32

#define SCL    2.8853900817779268f   // 2*log2(e): tanh(x) = 1 - 2/(exp2(SCL*x)+1)
#define SCLINV 0.3465735902799726f   // 1/SCL

typedef short  short8 __attribute__((ext_vector_type(8)));
typedef float  f32x16 __attribute__((ext_vector_type(16)));
typedef float  f32x2  __attribute__((ext_vector_type(2)));

// scalar f32 -> bf16 RNE (prepack)
__device__ __forceinline__ unsigned short f2bf(float f) {
    unsigned u = __float_as_uint(f);
    return (unsigned short)((u + 0x7FFFu + ((u >> 16) & 1u)) >> 16);
}

// packed f32 pair -> bf16x2 (v_cvt_pk_bf16_f32)
__device__ __forceinline__ unsigned pk2(float a, float b) {
    __hip_bfloat162 h = __float22bfloat162_rn(make_float2(a, b));
    return *reinterpret_cast<unsigned*>(&h);
}

// ---- kernel 0: prepack SCL*W2^T into bf16 MFMA A-fragment order ----
// lane l of chunk (mt,kstep) holds A[mt*32+(l&31)][kstep*16+(l>>5)*8+i]
// at wsA[((mt*16 + kstep)*64 + l)*8 + i]
__global__ void prepack_w2t(const float* __restrict__ W2, unsigned short* __restrict__ wsA) {
    const int k = blockIdx.x;
    const int j = threadIdx.x;
    const unsigned short b = f2bf(SCL * W2[k * HD + j]);
    const int kstep = k >> 4, kl = k & 15, hi2 = kl >> 3, i = kl & 7;
    const int mt = j >> 5, jl = j & 31;
    wsA[(((mt * 16) + kstep) * 64 + (hi2 * 32 + jl)) * 8 + i] = b;
}

// ---- kernel 1: tabulate dz = f(te,z), dd = df/dz(te,z) on the z-grid ----
// 288 blocks = 9 te x 32 chunks of 32 grid points; 512 threads; r8 MFMA engine.
__global__ __launch_bounds__(512, 4)
void build_table(const float* __restrict__ W1,
                 const float* __restrict__ b1,
                 const float* __restrict__ b2,
                 const float* __restrict__ W3,
                 const float* __restrict__ b3,
                 const unsigned short* __restrict__ wsA,
                 float2* __restrict__ tbl)
{
    __shared__ __align__(16) short Abuf[64 * 256];            // 32 KB
    __shared__ float w1zS[HD], w1tS[HD], b1S[HD], w0S[HD];    // 4 KB
    __shared__ float b2sc[HD], w3t[HD];                       // 2 KB
    __shared__ float2 kz[8][32];                              // 2 KB -> 40,960 B

    const int tid  = threadIdx.x;
    const int lane = tid & 63;
    const int c    = lane & 31;
    const int hi   = lane >> 5;
    const int wid  = tid >> 6;        // wave: j in [wid*32, wid*32+32)
    const int s    = tid & 31;        // grid point within chunk
    const int fb   = tid >> 5;        // staging feature block 0..15
    const int teI  = blockIdx.x / (G / 32);
    const int zblk = blockIdx.x % (G / 32);

    const float te = teI * 0.125f;
    const float zv = ZMIN + (float)(zblk * 32 + s) * HSTEP;

    if (tid < HD) {
        const float w0 = W1[tid];
        w1zS[tid] = SCL * w0;
        w1tS[tid] = SCL * W1[HD + tid];
        b1S[tid]  = SCL * b1[tid];
        w0S[tid]  = w0;
        b2sc[tid] = SCL * b2[tid];
        w3t[tid]  = W3[tid];
    }
    const float b3v = b3[0];

    // coalesced fragment load: 16 x dwordx4 per lane
    const short8* __restrict__ wsA8 = (const short8*)wsA;
    short8 w2f[16];
    #pragma unroll
    for (int kk = 0; kk < 16; ++kk)
        w2f[kk] = wsA8[(wid * 16 + kk) * 64 + lane];
    __syncthreads();

    const f32x2 one2 = {1.f, 1.f};
    const f32x2 m2   = {-2.f, -2.f};
    uint4* __restrict__ Ab4 = (uint4*)Abuf;
    const short8* __restrict__ Ab8 = (const short8*)Abuf;
    const int jb = wid * 32 + hi * 4;

    // ---- phase 1a: h1/th1 for the 32 grid points ----
    {
        const f32x2 zc2 = {zv, zv};
        const f32x2 te2 = {te, te};
        #pragma unroll
        for (int g2 = 0; g2 < 2; ++g2) {
            const int j0 = fb * 16 + g2 * 8;
            const float4 wzA = *(const float4*)&w1zS[j0];
            const float4 wzB = *(const float4*)&w1zS[j0 + 4];
            const float4 wtA = *(const float4*)&w1tS[j0];
            const float4 wtB = *(const float4*)&w1tS[j0 + 4];
            const float4 bbA = *(const float4*)&b1S[j0];
            const float4 bbB = *(const float4*)&b1S[j0 + 4];
            const float4 w0A = *(const float4*)&w0S[j0];
            const float4 w0B = *(const float4*)&w0S[j0 + 4];
            const f32x2 wz[4]  = {{wzA.x, wzA.y}, {wzA.z, wzA.w}, {wzB.x, wzB.y}, {wzB.z, wzB.w}};
            const f32x2 wt[4]  = {{wtA.x, wtA.y}, {wtA.z, wtA.w}, {wtB.x, wtB.y}, {wtB.z, wtB.w}};
            const f32x2 bb[4]  = {{bbA.x, bbA.y}, {bbA.z, bbA.w}, {bbB.x, bbB.y}, {bbB.z, bbB.w}};
            const f32x2 w0p[4] = {{w0A.x, w0A.y}, {w0A.z, w0A.w}, {w0B.x, w0B.y}, {w0B.z, w0B.w}};
            f32x2 hh[4], th[4];
            #pragma unroll
            for (int pp = 0; pp < 4; ++pp) {
                const f32x2 a = __builtin_elementwise_fma(zc2, wz[pp],
                                  __builtin_elementwise_fma(te2, wt[pp], bb[pp]));
                f32x2 ev; ev.x = __builtin_amdgcn_exp2f(a.x);
                          ev.y = __builtin_amdgcn_exp2f(a.y);
                const f32x2 e1 = ev + one2;
                f32x2 rv; rv.x = __builtin_amdgcn_rcpf(e1.x);
                          rv.y = __builtin_amdgcn_rcpf(e1.y);
                const f32x2 h  = __builtin_elementwise_fma(m2, rv, one2);   // tanh
                const f32x2 t1 = __builtin_elementwise_fma(-h, h, one2);    // 1 - h^2
                hh[pp] = h;
                th[pp] = t1 * w0p[pp];
            }
            uint4 vU, vT;
            vU.x = pk2(hh[0].x, hh[0].y);  vU.y = pk2(hh[1].x, hh[1].y);
            vU.z = pk2(hh[2].x, hh[2].y);  vU.w = pk2(hh[3].x, hh[3].y);
            vT.x = pk2(th[0].x, th[0].y);  vT.y = pk2(th[1].x, th[1].y);
            vT.z = pk2(th[2].x, th[2].y);  vT.w = pk2(th[3].x, th[3].y);
            const int gr = j0 >> 3;
            Ab4[gr * 64 + s]      = vU;
            Ab4[gr * 64 + 32 + s] = vT;
        }
    }
    __syncthreads();

    // ---- phase 1b: MFMA ----
    f32x16 accU, accT;
    #pragma unroll
    for (int rq = 0; rq < 4; ++rq) {
        const float4 bq = *(const float4*)&b2sc[jb + rq * 8];
        accU[rq * 4 + 0] = bq.x;  accU[rq * 4 + 1] = bq.y;
        accU[rq * 4 + 2] = bq.z;  accU[rq * 4 + 3] = bq.w;
        accT[rq * 4 + 0] = 0.f;   accT[rq * 4 + 1] = 0.f;
        accT[rq * 4 + 2] = 0.f;   accT[rq * 4 + 3] = 0.f;
    }
    #pragma unroll
    for (int kk = 0; kk < 16; ++kk) {
        const short8 hU = Ab8[(kk * 2 + hi) * 64 + c];
        const short8 hT = Ab8[(kk * 2 + hi) * 64 + 32 + c];
        accU = __builtin_amdgcn_mfma_f32_32x32x16_bf16(w2f[kk], hU, accU, 0, 0, 0);
        accT = __builtin_amdgcn_mfma_f32_32x32x16_bf16(w2f[kk], hT, accT, 0, 0, 0);
    }

    // ---- phase 1c: epilogue ----
    f32x2 pz2 = {0.f, 0.f}, pd2 = {0.f, 0.f};
    #pragma unroll
    for (int rq = 0; rq < 4; ++rq) {
        const float4 w3q = *(const float4*)&w3t[jb + rq * 8];
        const f32x2 w3p[2] = {{w3q.x, w3q.y}, {w3q.z, w3q.w}};
        #pragma unroll
        for (int pr = 0; pr < 2; ++pr) {
            const int r = rq * 4 + pr * 2;
            const f32x2 u2 = {accU[r], accU[r + 1]};
            const f32x2 t2 = {accT[r], accT[r + 1]};
            f32x2 ev; ev.x = __builtin_amdgcn_exp2f(u2.x);
                      ev.y = __builtin_amdgcn_exp2f(u2.y);
            const f32x2 e1 = ev + one2;
            f32x2 rv; rv.x = __builtin_amdgcn_rcpf(e1.x);
                      rv.y = __builtin_amdgcn_rcpf(e1.y);
            const f32x2 h2 = __builtin_elementwise_fma(m2, rv, one2);
            const f32x2 hq = h2 * h2;
            const f32x2 th2 = __builtin_elementwise_fma(-hq, t2, t2);
            pz2 = __builtin_elementwise_fma(h2,  w3p[pr], pz2);
            pd2 = __builtin_elementwise_fma(th2, w3p[pr], pd2);
        }
    }
    float pdz = pz2.x + pz2.y;
    float pdd = (pd2.x + pd2.y) * SCLINV;
    pdz += __shfl_xor(pdz, 32);
    pdd += __shfl_xor(pdd, 32);
    if (hi == 0) kz[wid][c] = make_float2(pdz, pdd);
    __syncthreads();

    if (tid < 32) {
        float kzs = b3v, kds = 0.f;
        #pragma unroll
        for (int w = 0; w < 8; ++w) {
            const float2 a = kz[w][tid];
            kzs += a.x; kds += a.y;
        }
        tbl[teI * G + zblk * 32 + tid] = make_float2(kzs, kds);
    }
}

// ---- kernel 2: RK4 integration; ALL 9 slices resident in LDS (one load) ----
__global__ __launch_bounds__(256)
void integrate(const float* __restrict__ z0,
               const float2* __restrict__ tbl,
               float* __restrict__ out)
{
    __shared__ float2 sl[NTE * G];           // 73,728 B: the whole table
    const int tid = threadIdx.x;
    const int sid = blockIdx.x * 256 + tid;

    // one coalesced load of the full table (18 x float4 per thread)
    {
        float4* __restrict__ d = (float4*)sl;
        const float4* __restrict__ g = (const float4*)tbl;
        #pragma unroll
        for (int i = 0; i < (NTE * G) / 2 / 256; ++i)
            d[i * 256 + tid] = g[i * 256 + tid];
    }
    float zb = z0[sid];
    __syncthreads();

    float zc = zb, skz = 0.f, skd = 0.f, dacc = 0.f;
    const float dt = 0.25f;

    #pragma unroll
    for (int it = 0; it < 16; ++it) {
        const int st = it >> 2, e = it & 3;
        const int base = (2 * st + ((e == 0) ? 0 : (e == 3) ? 2 : 1)) * G;

        float xf = (zc - ZMIN) * INVH;
        xf = fminf(fmaxf(xf, 0.0f), (float)(G - 1));
        int i0 = (int)xf;
        if (i0 > G - 2) i0 = G - 2;
        const float w  = xf - (float)i0;
        const float2 a = sl[base + i0];
        const float2 b = sl[base + i0 + 1];
        const float kzv = fmaf(w, b.x - a.x, a.x);
        const float kdv = fmaf(w, b.y - a.y, a.y);

        const float cw = (e == 1 || e == 2) ? 2.f : 1.f;
        skz += cw * kzv;
        skd += cw * kdv;
        if (e < 3) {
            zc = fmaf((e == 2) ? dt : 0.5f * dt, kzv, zb);
        } else {
            zb   = fmaf(dt / 6.f, skz, zb);
            zc   = zb;
            dacc = fmaf(dt / 6.f, skd, dacc);
            skz = 0.f; skd = 0.f;
        }
    }

    out[sid]         = zb;      // zf
    out[BATCH + sid] = dacc;    // div_int
}

extern "C" void kernel_launch(void* const* d_in, const int* in_sizes, int n_in,
                              void* d_out, int out_size, void* d_ws, size_t ws_size,
                              hipStream_t stream) {
    const float* z0 = (const float*)d_in[0];
    const float* W1 = (const float*)d_in[1];
    const float* b1 = (const float*)d_in[2];
    const float* W2 = (const float*)d_in[3];
    const float* b2 = (const float*)d_in[4];
    const float* W3 = (const float*)d_in[5];
    const float* b3 = (const float*)d_in[6];
    float* out = (float*)d_out;

    float2* tbl = (float2*)d_ws;                                    // 73,728 B @ 0
    unsigned short* wsA = (unsigned short*)((char*)d_ws + 131072);  // 128 KB frag W2^T

    hipLaunchKernelGGL(prepack_w2t, dim3(HD), dim3(HD), 0, stream, W2, wsA);
    hipLaunchKernelGGL(build_table, dim3(NTE * (G / 32)), dim3(512), 0, stream,
                       W1, b1, b2, W3, b3, wsA, tbl);
    hipLaunchKernelGGL(integrate, dim3(BATCH / 256), dim3(256), 0, stream,
                       z0, tbl, out);
}